// Round 1
// baseline (82.792 us; speedup 1.0000x reference)
//
#include <hip/hip_runtime.h>
#include <math.h>

#define NQ 10
#define NL 4
#define NSTATE 1024

// Kernel 1: simulate the shared 4-layer circuit on |0...0> (1024 real amps),
// then emit A_q = <v|Z_q|v>, B_q = <v|X_q|v>  (20 floats into ws).
// One block, 1024 threads, one state element per thread, double-buffered LDS
// (1 barrier per gate).
__global__ __launch_bounds__(1024) void qc_prepare(const float* __restrict__ params,
                                                   float* __restrict__ ab) {
    __shared__ float bufA[NSTATE];
    __shared__ float bufB[NSTATE];
    __shared__ float wz[16][NQ];
    __shared__ float wx[16][NQ];
    const int tid = threadIdx.x;
    float* cur = bufA;
    float* nxt = bufB;
    cur[tid] = (tid == 0) ? 1.0f : 0.0f;
    __syncthreads();

    for (int l = 0; l < NL; ++l) {
        // RY(params[l,q]) on every qubit. qubit q <-> bit (9-q).
        for (int q = 0; q < NQ; ++q) {
            const float th = 0.5f * params[l * NQ + q];
            const float c = cosf(th);
            const float s = sinf(th);
            const int m = 1 << (9 - q);
            const float me = cur[tid];
            const float pa = cur[tid ^ m];
            // pair (s0,s1): new0 = c*v0 - s*v1 ; new1 = s*v0 + c*v1
            nxt[tid] = (tid & m) ? fmaf(s, pa, c * me) : fmaf(-s, pa, c * me);
            __syncthreads();
            float* t = cur; cur = nxt; nxt = t;
        }
        // CNOT(q, q+1) for q=0..8, then CNOT(9, 0): gather permutation.
        for (int q = 0; q < NQ; ++q) {
            const int mc = 1 << (9 - q);
            const int mt = (q == NQ - 1) ? (1 << 9) : (1 << (8 - q));
            nxt[tid] = cur[(tid & mc) ? (tid ^ mt) : tid];
            __syncthreads();
            float* t = cur; cur = nxt; nxt = t;
        }
    }

    // A_q = sum_s (+-) v_s^2 ; B_q = sum_s v_s * v_{s^m}  (= 2*sum_pairs v0*v1)
    const float v = cur[tid];
    const int wave = tid >> 6;
    const int lane = tid & 63;
    for (int q = 0; q < NQ; ++q) {
        const int m = 1 << (9 - q);
        float za = (tid & m) ? -(v * v) : (v * v);
        float xb = v * cur[tid ^ m];
#pragma unroll
        for (int off = 32; off > 0; off >>= 1) {
            za += __shfl_down(za, off);
            xb += __shfl_down(xb, off);
        }
        if (lane == 0) { wz[wave][q] = za; wx[wave][q] = xb; }
    }
    __syncthreads();
    if (tid < NQ) {
        float A = 0.0f, Bx = 0.0f;
#pragma unroll
        for (int w = 0; w < 16; ++w) { A += wz[w][tid]; Bx += wx[w][tid]; }
        ab[tid]      = A;
        ab[NQ + tid] = Bx;
    }
}

// Kernel 2: out[i,h] = (h<10) ? cos(x[i,h])*A_h - sin(x[i,h])*B_h : 0
// float4 stores over the (4,1024,64) output; one float4 per thread.
__global__ __launch_bounds__(256) void qc_output(const float* __restrict__ x,
                                                 const float* __restrict__ ab,
                                                 float* __restrict__ out,
                                                 int total4) {
    const int i = blockIdx.x * 256 + threadIdx.x;
    if (i >= total4) return;
    const int h0 = (i << 2) & 63;  // feature index of component .x
    float4 o = make_float4(0.0f, 0.0f, 0.0f, 0.0f);
    if (h0 < NQ) {  // h0 in {0,4,8}
        const float4 xv = reinterpret_cast<const float4*>(x)[i];
        o.x = __cosf(xv.x) * ab[h0]     - __sinf(xv.x) * ab[NQ + h0];
        o.y = __cosf(xv.y) * ab[h0 + 1] - __sinf(xv.y) * ab[NQ + h0 + 1];
        if (h0 + 2 < NQ) {
            o.z = __cosf(xv.z) * ab[h0 + 2] - __sinf(xv.z) * ab[NQ + h0 + 2];
            o.w = __cosf(xv.w) * ab[h0 + 3] - __sinf(xv.w) * ab[NQ + h0 + 3];
        }
    }
    reinterpret_cast<float4*>(out)[i] = o;
}

extern "C" void kernel_launch(void* const* d_in, const int* in_sizes, int n_in,
                              void* d_out, int out_size, void* d_ws, size_t ws_size,
                              hipStream_t stream) {
    const float* x      = (const float*)d_in[0];   // (4,1024,64) f32
    const float* params = (const float*)d_in[1];   // (4,10) f32
    float* out = (float*)d_out;                    // (4,1024,64) f32
    float* ab  = (float*)d_ws;                     // 20 floats scratch

    qc_prepare<<<1, 1024, 0, stream>>>(params, ab);

    const int total4 = out_size / 4;  // 65536 float4s
    qc_output<<<(total4 + 255) / 256, 256, 0, stream>>>(x, ab, out, total4);
}

// Round 2
// 64.361 us; speedup vs baseline: 1.2864x; 1.2864x over previous
//
#include <hip/hip_runtime.h>
#include <math.h>

#define NQ 10
#define NL 4

// Fused kernel. Phase 1 (wave 0 of every block, redundantly): simulate the
// shared 4-layer circuit on |0..0> entirely in one wave's registers
// (16 amps/lane; s bits [9:4]=lane -> qubits 0..5 via shfl_xor, bits [3:0]=
// register -> qubits 6..9 in-register; CNOT ring = one composed permutation
// gathered through wave-private LDS, no barriers). Emits A_q=<v|Z_q|v>,
// B_q=<v|X_q|v> to LDS. Phase 2 (all 256 threads): out[i,h] =
// cos(x)*A_h - sin(x)*B_h for h<10, else 0 (RY Heisenberg: Z -> cosZ - sinX).
__global__ __launch_bounds__(256) void qc_fused(const float* __restrict__ x,
                                                const float* __restrict__ params,
                                                float* __restrict__ out) {
    __shared__ float sA[NQ];
    __shared__ float sB[NQ];
    __shared__ float csc[NL * NQ];
    __shared__ float css[NL * NQ];
    __shared__ float perm_buf[1024];

    const int tid = threadIdx.x;

    if (tid < 64) {
        const int lane = tid;
        // trig for the 40 shared gates, once
        if (lane < NL * NQ) {
            float sv, cv;
            sincosf(0.5f * params[lane], &sv, &cv);
            csc[lane] = cv;
            css[lane] = sv;
        }
        __asm__ volatile("s_waitcnt lgkmcnt(0)" ::: "memory");

        // Composed CNOT-ring permutation (identical every layer).
        // Sequential gathers new[s]=old[sigma_q(s)], q=0..9 compose to
        // P = sigma_0(sigma_1(...sigma_9(s))): apply sigma_9 first.
        int pidx[16];
#pragma unroll
        for (int r = 0; r < 16; ++r) {
            int t = lane * 16 + r;
            t ^= (t & 1) << 9;                      // gate 9: CNOT(q9->q0): cb=0, tb=9
#pragma unroll
            for (int j = 8; j >= 0; --j)            // gate j: cb=9-j, tb=8-j
                t ^= ((t >> (9 - j)) & 1) << (8 - j);
            pidx[r] = (t & 15) * 64 + (t >> 4);     // pre-swizzled [r][lane] layout
        }

        float v[16];
#pragma unroll
        for (int r = 0; r < 16; ++r) v[r] = 0.0f;
        if (lane == 0) v[0] = 1.0f;

#pragma unroll
        for (int l = 0; l < NL; ++l) {
            // RY on lane-bit qubits q=0..5 (s-bit 9-q = lane-bit 5-q)
#pragma unroll
            for (int q = 0; q < 6; ++q) {
                const float c = csc[l * NQ + q];
                const float s = css[l * NQ + q];
                const float t = ((lane >> (5 - q)) & 1) ? s : -s;
#pragma unroll
                for (int r = 0; r < 16; ++r) {
                    const float p = __shfl_xor(v[r], 1 << (5 - q), 64);
                    v[r] = fmaf(t, p, c * v[r]);    // lo: c*v0-s*v1 ; hi: s*v0+c*v1
                }
            }
            // RY on register-bit qubits q=6..9 (mask 1<<(9-q))
#pragma unroll
            for (int q = 6; q < NQ; ++q) {
                const float c = csc[l * NQ + q];
                const float s = css[l * NQ + q];
                const int mr = 1 << (9 - q);
#pragma unroll
                for (int r = 0; r < 16; ++r) {
                    if (!(r & mr)) {
                        const float v0 = v[r], v1 = v[r | mr];
                        v[r]      = fmaf(-s, v1, c * v0);
                        v[r | mr] = fmaf( s, v0, c * v1);
                    }
                }
            }
            // CNOT ring: single gather through wave-private LDS (no barrier;
            // DS ops from one wave are pipeline-ordered). Swizzled stride-64
            // writes are bank-conflict-free (2 lanes/bank).
#pragma unroll
            for (int r = 0; r < 16; ++r) perm_buf[r * 64 + lane] = v[r];
            __asm__ volatile("s_waitcnt lgkmcnt(0)" ::: "memory");
#pragma unroll
            for (int r = 0; r < 16; ++r) v[r] = perm_buf[pidx[r]];
            __asm__ volatile("s_waitcnt lgkmcnt(0)" ::: "memory");
        }

        // A_q = sum_s (+-)v_s^2 ; B_q = sum_s v_s * v_{s^m}
        float E = 0.0f;
#pragma unroll
        for (int r = 0; r < 16; ++r) E = fmaf(v[r], v[r], E);

        float pA[NQ], pB[NQ];
#pragma unroll
        for (int q = 0; q < 6; ++q) {
            float b = 0.0f;
#pragma unroll
            for (int r = 0; r < 16; ++r) {
                const float p = __shfl_xor(v[r], 1 << (5 - q), 64);
                b = fmaf(v[r], p, b);
            }
            pA[q] = ((lane >> (5 - q)) & 1) ? -E : E;
            pB[q] = b;
        }
#pragma unroll
        for (int q = 6; q < NQ; ++q) {
            const int mr = 1 << (9 - q);
            float a = 0.0f, b = 0.0f;
#pragma unroll
            for (int r = 0; r < 16; ++r) {
                a += ((r & mr) ? -1.0f : 1.0f) * v[r] * v[r];
                b = fmaf(v[r], v[r ^ mr], b);
            }
            pA[q] = a;
            pB[q] = b;
        }
#pragma unroll
        for (int q = 0; q < NQ; ++q) {
            float a = pA[q], b = pB[q];
#pragma unroll
            for (int off = 32; off > 0; off >>= 1) {
                a += __shfl_xor(a, off, 64);
                b += __shfl_xor(b, off, 64);
            }
            if (lane == 0) { sA[q] = a; sB[q] = b; }
        }
    }
    __syncthreads();

    // Phase 2: one float4 of output per thread.
    const int i = blockIdx.x * 256 + tid;
    const int h0 = (i << 2) & 63;               // feature index of component .x
    float4 o = make_float4(0.f, 0.f, 0.f, 0.f);
    if (h0 < 12) {                              // h0 in {0,4,8}
        const float4 xv = reinterpret_cast<const float4*>(x)[i];
        float sv, cv;
        sincosf(xv.x, &sv, &cv); o.x = cv * sA[h0]     - sv * sB[h0];
        sincosf(xv.y, &sv, &cv); o.y = cv * sA[h0 + 1] - sv * sB[h0 + 1];
        if (h0 + 2 < NQ) {
            sincosf(xv.z, &sv, &cv); o.z = cv * sA[h0 + 2] - sv * sB[h0 + 2];
            sincosf(xv.w, &sv, &cv); o.w = cv * sA[h0 + 3] - sv * sB[h0 + 3];
        }
    }
    reinterpret_cast<float4*>(out)[i] = o;
}

extern "C" void kernel_launch(void* const* d_in, const int* in_sizes, int n_in,
                              void* d_out, int out_size, void* d_ws, size_t ws_size,
                              hipStream_t stream) {
    const float* x      = (const float*)d_in[0];   // (4,1024,64) f32
    const float* params = (const float*)d_in[1];   // (4,10) f32
    float* out = (float*)d_out;                    // (4,1024,64) f32

    const int total4 = out_size / 4;               // 65536 float4s
    qc_fused<<<total4 / 256, 256, 0, stream>>>(x, params, out);
}